// Round 1
// baseline (119.591 us; speedup 1.0000x reference)
//
#include <hip/hip_runtime.h>

// out[b,0,i,j] = sigmoid(cos(pi*x[b,0,i,j] + w[0]) - thr[0]),  i,j in [0,510)
// x: (64,1,512,512) fp32, out: (64,1,510,510) fp32. Memory-bound elementwise.

#define BATCH 64
#define H_IN 512
#define W_IN 512
#define H_OUT 510
#define W_OUT 510
#define W_OUT_V2 (W_OUT / 2)   // 255 float2 per output row

__global__ void __launch_bounds__(256) conv154_kernel(
        const float* __restrict__ x,
        const float* __restrict__ weight,
        const float* __restrict__ threshold,
        float* __restrict__ out) {
    const float w0  = weight[0];
    const float thr = threshold[0];
    const float PI  = 3.14159265358979323846f;

    const int total = BATCH * H_OUT * W_OUT_V2;       // 8,323,200 float2 elems
    const int stride = gridDim.x * blockDim.x;
    for (int idx = blockIdx.x * blockDim.x + threadIdx.x; idx < total; idx += stride) {
        const int j2 = idx % W_OUT_V2;
        const int t  = idx / W_OUT_V2;
        const int i  = t % H_OUT;
        const int b  = t / H_OUT;

        const size_t in_off  = (size_t)b * (H_IN * W_IN)   + (size_t)i * W_IN  + j2 * 2;
        const size_t out_off = (size_t)b * (H_OUT * W_OUT) + (size_t)i * W_OUT + j2 * 2;

        const float2 v = *reinterpret_cast<const float2*>(x + in_off);

        float2 r;
        const float c0 = __cosf(fmaf(v.x, PI, w0));
        const float c1 = __cosf(fmaf(v.y, PI, w0));
        r.x = 1.0f / (1.0f + __expf(thr - c0));   // sigmoid(c0 - thr)
        r.y = 1.0f / (1.0f + __expf(thr - c1));

        *reinterpret_cast<float2*>(out + out_off) = r;
    }
}

extern "C" void kernel_launch(void* const* d_in, const int* in_sizes, int n_in,
                              void* d_out, int out_size, void* d_ws, size_t ws_size,
                              hipStream_t stream) {
    const float* x   = (const float*)d_in[0];
    const float* w   = (const float*)d_in[1];
    const float* thr = (const float*)d_in[2];
    float* out       = (float*)d_out;

    const int total  = BATCH * H_OUT * W_OUT_V2;
    const int block  = 256;
    int grid = (total + block - 1) / block;
    if (grid > 4096) grid = 4096;                 // grid-stride the rest
    conv154_kernel<<<grid, block, 0, stream>>>(x, w, thr, out);
}

// Round 3
// 112.815 us; speedup vs baseline: 1.0601x; 1.0601x over previous
//
#include <hip/hip_runtime.h>

// out[b,0,i,j] = sigmoid(cos(pi*x[b,0,i,j] + w[0]) - thr[0]),  i,j in [0,510)
// x: (64,1,512,512) fp32, out: (64,1,510,510) fp32. Memory-bound elementwise.
//
// Layout: 1 block (256 thr) = 2 output rows; 128 threads/row x 4 floats
// (dwordx4 load+store). Thread 127 clamps to col 506 -> cols 506/507 written
// twice with identical bits (benign). Multi-dword global ops need only dword
// alignment on CDNA, so 8B-aligned row bases are fine.

#define BATCH 64
#define H_IN 512
#define W_IN 512
#define H_OUT 510
#define W_OUT 510
#define ROWS_TOTAL (BATCH * H_OUT)        // 32640
#define ROWS_PER_BLOCK 2

struct f4 { float x, y, z, w; };

__global__ void __launch_bounds__(256) conv154_kernel(
        const float* __restrict__ x,
        const float* __restrict__ weight,
        const float* __restrict__ threshold,
        float* __restrict__ out) {
    const float w0  = weight[0];
    const float thr = threshold[0];
    const float PI  = 3.14159265358979323846f;

    const int t   = threadIdx.x;
    const int row = blockIdx.x * ROWS_PER_BLOCK + (t >> 7);   // global row in [0, 32640)
    const int j   = t & 127;
    int col = j * 4;
    if (col > W_OUT - 4) col = W_OUT - 4;                     // 506: overlap tail

    const int b = row / H_OUT;            // magic-mul, once per thread
    const int i = row - b * H_OUT;

    const float* in_p  = x   + (size_t)b * (H_IN * W_IN) + (size_t)i * W_IN + col;
    float*       out_p = out + (size_t)row * W_OUT + col;

    const f4 v = *reinterpret_cast<const f4*>(in_p);

    f4 r;
    #pragma unroll
    for (int k = 0; k < 4; ++k) {
        const float xv = (&v.x)[k];
        const float c  = __cosf(fmaf(xv, PI, w0));
        const float e  = __expf(thr - c);
        (&r.x)[k] = __builtin_amdgcn_rcpf(1.0f + e);          // sigmoid(c - thr)
    }

    *reinterpret_cast<f4*>(out_p) = r;
}

extern "C" void kernel_launch(void* const* d_in, const int* in_sizes, int n_in,
                              void* d_out, int out_size, void* d_ws, size_t ws_size,
                              hipStream_t stream) {
    const float* x   = (const float*)d_in[0];
    const float* w   = (const float*)d_in[1];
    const float* thr = (const float*)d_in[2];
    float* out       = (float*)d_out;

    const int grid = ROWS_TOTAL / ROWS_PER_BLOCK;   // 16320 blocks, exact
    conv154_kernel<<<grid, 256, 0, stream>>>(x, w, thr, out);
}